// Round 2
// baseline (235.720 us; speedup 1.0000x reference)
//
#include <hip/hip_runtime.h>
#include <math.h>

#define CC 512
#define HH 64
#define WW 96
#define NN 16
#define HW (HH*WW)        // 6144
#define NA 9
#define NLOC 36
#define NSC 18

// wT2 layout in d_ws (all rows 16B-aligned for s_load_dwordx4/x8):
//   loc group og=0,1,2 : base og*CC*16, row stride 16 floats, 12 used
//   score group        : base 3*CC*16,  row stride 32 floats, 18 used
#define LOC_STRIDE 16
#define SC_STRIDE  32
#define SC_BASE    (3 * CC * LOC_STRIDE)

// ---------------------------------------------------------------------------
// Kernel 1: scatter weights into the padded transposed layout.
// ---------------------------------------------------------------------------
__global__ void transpose_w_kernel(const float* __restrict__ lw,
                                   const float* __restrict__ sw,
                                   float* __restrict__ wT2) {
    int i = blockIdx.x * 256 + threadIdx.x;   // over CC*54
    if (i >= CC * 54) return;
    int c = i / 54, o = i % 54;
    if (o < NLOC) {
        int og = o / 12, j = o % 12;
        wT2[og * CC * LOC_STRIDE + c * LOC_STRIDE + j] = lw[o * CC + c];
    } else {
        int j = o - NLOC;
        wT2[SC_BASE + c * SC_STRIDE + j] = sw[j * CC + c];
    }
}

// ---------------------------------------------------------------------------
// Kernel 2: anchors (55296, 4), closed form, f64 to match numpy.
// ---------------------------------------------------------------------------
__global__ void anchors_kernel(float* __restrict__ out3) {
    int t = blockIdx.x * 256 + threadIdx.x;   // over HW*NA
    if (t >= HW * NA) return;
    int a   = t % NA;
    int rem = t / NA;
    int h = rem / WW, w = rem % WW;
    int ri = a / 3, si = a % 3;
    const double ratios[3] = {0.5, 1.0, 2.0};
    const double scales[3] = {8.0, 16.0, 32.0};
    double ha = 16.0 * scales[si] * sqrt(ratios[ri]);
    double wa = 16.0 * scales[si] * sqrt(1.0 / ratios[ri]);
    float y1 = (float)(8.0 - ha * 0.5);
    float x1 = (float)(8.0 - wa * 0.5);
    float y2 = (float)(8.0 + ha * 0.5);
    float x2 = (float)(8.0 + wa * 0.5);
    float sy = (float)(h * 16);
    float sx = (float)(w * 16);
    float4 v = make_float4(sy + y1, sx + x1, sy + y2, sx + x2);
    *reinterpret_cast<float4*>(out3 + (size_t)t * 4) = v;
}

// ---------------------------------------------------------------------------
// Kernel 3: main GEMM-ish kernel.
// Block = 256 threads = 4 waves, all covering the SAME 64 positions:
//   wave 0..2 -> loc outputs [12*og, 12*og+12)
//   wave 3    -> score outputs [0,18) + softmax epilogue
// x loads: lane = consecutive position -> coalesced 256B/wave; the 4 waves
// read identical lines (L1/L2 hits). Weights: wave-uniform -> scalar loads.
// Grid = 1536 blocks * 4 waves = 6144 waves -> ~75% occupancy.
// ---------------------------------------------------------------------------
template<int NO, int WSTRIDE>
__device__ __forceinline__ void rpn_accum(const float* __restrict__ xp,
                                          const float* __restrict__ wbase,
                                          float* acc) {
    #pragma unroll
    for (int o = 0; o < NO; ++o) acc[o] = 0.0f;
    #pragma unroll 8
    for (int c = 0; c < CC; ++c) {
        float xv = xp[(size_t)c * HW];
        const float* wr = wbase + c * WSTRIDE;   // wave-uniform, aligned
        #pragma unroll
        for (int o = 0; o < NO; ++o)
            acc[o] = fmaf(xv, wr[o], acc[o]);
    }
}

__launch_bounds__(256)
__global__ void rpn_main_kernel(const float* __restrict__ x,
                                const float* __restrict__ wT2,
                                const float* __restrict__ lb,
                                const float* __restrict__ sb,
                                float* __restrict__ out0,   // rpn_loc
                                float* __restrict__ out1,   // rpn_score
                                float* __restrict__ out2) { // rpn_fg_scores
    int lane = threadIdx.x & 63;
    int og   = threadIdx.x >> 6;                 // wave id = output group
    int p    = blockIdx.x * 64 + lane;           // position in [0, NN*HW)
    int n    = p / HW;
    int rem  = p % HW;
    const float* xp = x + (size_t)n * CC * HW + rem;

    if (og < 3) {
        float acc[12];
        rpn_accum<12, LOC_STRIDE>(xp, wT2 + og * CC * LOC_STRIDE, acc);
        int ob = og * 12;
        size_t base = (size_t)p * NLOC + ob;
        #pragma unroll
        for (int j = 0; j < 12; ++j)
            out0[base + j] = acc[j] + lb[ob + j];
    } else {
        float acc[18];
        rpn_accum<18, SC_STRIDE>(xp, wT2 + SC_BASE, acc);
        float sc[18];
        size_t base1 = (size_t)p * NSC;
        #pragma unroll
        for (int j = 0; j < 18; ++j) {
            sc[j] = acc[j] + sb[j];
            out1[base1 + j] = sc[j];
        }
        size_t base2 = (size_t)p * NA;
        #pragma unroll
        for (int a = 0; a < NA; ++a) {
            float d = sc[2 * a] - sc[2 * a + 1];          // s0 - s1
            out2[base2 + a] = 1.0f / (1.0f + __expf(d));  // softmax[...,1]
        }
    }
}

extern "C" void kernel_launch(void* const* d_in, const int* in_sizes, int n_in,
                              void* d_out, int out_size, void* d_ws, size_t ws_size,
                              hipStream_t stream) {
    const float* x  = (const float*)d_in[0];
    const float* lw = (const float*)d_in[1];
    const float* lb = (const float*)d_in[2];
    const float* sw = (const float*)d_in[3];
    const float* sb = (const float*)d_in[4];

    float* out0 = (float*)d_out;                          // (16, 55296, 4)
    float* out1 = out0 + (size_t)NN * HW * NLOC;          // (16, 64, 96, 18)
    float* out2 = out1 + (size_t)NN * HW * NSC;           // (16, 55296)
    float* out3 = out2 + (size_t)NN * HW * NA;            // (55296, 4)

    float* wT2 = (float*)d_ws;   // (3*CC*16 + CC*32) floats = 160 KB

    int grid_t = (CC * 54 + 255) / 256;
    transpose_w_kernel<<<grid_t, 256, 0, stream>>>(lw, sw, wT2);

    int grid_a = (HW * NA + 255) / 256;
    anchors_kernel<<<grid_a, 256, 0, stream>>>(out3);

    int grid_m = NN * HW / 64;   // 1536 blocks * 4 waves
    rpn_main_kernel<<<grid_m, 256, 0, stream>>>(x, wT2, lb, sb, out0, out1, out2);
}

// Round 3
// 98.258 us; speedup vs baseline: 2.3990x; 2.3990x over previous
//
#include <hip/hip_runtime.h>
#include <math.h>

#define CC 512
#define HH 64
#define WW 96
#define NN 16
#define HW (HH*WW)        // 6144
#define NA 9
#define NLOC 36
#define NSC 18

// Balanced output groups per wave: {14, 14, 14, 12}
//   g0: o 0..13   (loc 0..13)
//   g1: o 14..27  (loc 14..27)
//   g2: o 28..41  (loc 28..35 + score 0..5)
//   g3: o 42..53  (score 6..17)
// wT3 layout: group g base = g*CC*16 floats; row c = 16 floats (64B aligned)
#define GSTRIDE 16

// ---------------------------------------------------------------------------
// Kernel 1: scatter weights into padded per-group transposed layout.
// ---------------------------------------------------------------------------
__global__ void transpose_w_kernel(const float* __restrict__ lw,
                                   const float* __restrict__ sw,
                                   float* __restrict__ wT3) {
    int i = blockIdx.x * 256 + threadIdx.x;   // over CC*54
    if (i >= CC * 54) return;
    int c = i / 54, o = i % 54;
    int g = (o < 14) ? 0 : (o < 28) ? 1 : (o < 42) ? 2 : 3;
    int j = o - g * 14;                        // g3 base is 42 = 3*14, works
    float v = (o < NLOC) ? lw[o * CC + c] : sw[(o - NLOC) * CC + c];
    wT3[(size_t)g * CC * GSTRIDE + c * GSTRIDE + j] = v;
}

// ---------------------------------------------------------------------------
// Kernel 2: anchors (55296, 4), closed form, f64 to match numpy.
// ---------------------------------------------------------------------------
__global__ void anchors_kernel(float* __restrict__ out3) {
    int t = blockIdx.x * 256 + threadIdx.x;   // over HW*NA
    if (t >= HW * NA) return;
    int a   = t % NA;
    int rem = t / NA;
    int h = rem / WW, w = rem % WW;
    int ri = a / 3, si = a % 3;
    const double ratios[3] = {0.5, 1.0, 2.0};
    const double scales[3] = {8.0, 16.0, 32.0};
    double ha = 16.0 * scales[si] * sqrt(ratios[ri]);
    double wa = 16.0 * scales[si] * sqrt(1.0 / ratios[ri]);
    float y1 = (float)(8.0 - ha * 0.5);
    float x1 = (float)(8.0 - wa * 0.5);
    float y2 = (float)(8.0 + ha * 0.5);
    float x2 = (float)(8.0 + wa * 0.5);
    float sy = (float)(h * 16);
    float sx = (float)(w * 16);
    float4 v = make_float4(sy + y1, sx + x1, sy + y2, sx + x2);
    *reinterpret_cast<float4*>(out3 + (size_t)t * 4) = v;
}

// ---------------------------------------------------------------------------
// Kernel 3: main. Block = 256 = 4 waves over the SAME 64 positions.
// Wave g computes its 12-14 outputs. Weight base made provably uniform via
// readfirstlane -> s_load (scalar cache, zero TA cost). x-load is the only
// VMEM per c -> VALU-bound inner loop.
// ---------------------------------------------------------------------------
template<int NO>
__device__ __forceinline__ void rpn_accum(const float* __restrict__ xp,
                                          const float* __restrict__ wbase,
                                          float* acc) {
    #pragma unroll
    for (int o = 0; o < NO; ++o) acc[o] = 0.0f;
    #pragma unroll 4
    for (int c = 0; c < CC; ++c) {
        float xv = xp[(size_t)c * HW];
        const float* wr = wbase + c * GSTRIDE;   // uniform (SGPR) base
        #pragma unroll
        for (int o = 0; o < NO; ++o)
            acc[o] = fmaf(xv, wr[o], acc[o]);
    }
}

__launch_bounds__(256)
__global__ void rpn_main_kernel(const float* __restrict__ x,
                                const float* __restrict__ wT3,
                                const float* __restrict__ lb,
                                const float* __restrict__ sb,
                                float* __restrict__ out0,   // rpn_loc
                                float* __restrict__ out1,   // rpn_score
                                float* __restrict__ out2) { // rpn_fg_scores
    int lane = threadIdx.x & 63;
    int og   = __builtin_amdgcn_readfirstlane(threadIdx.x >> 6); // uniform
    int p    = blockIdx.x * 64 + lane;           // position in [0, NN*HW)
    int n    = p / HW;
    int rem  = p % HW;
    const float* xp    = x + (size_t)n * CC * HW + rem;
    const float* wbase = wT3 + (size_t)og * CC * GSTRIDE;

    if (og == 3) {
        // scores 6..17
        float acc[12];
        rpn_accum<12>(xp, wbase, acc);
        float sc[12];
        size_t base1 = (size_t)p * NSC;
        #pragma unroll
        for (int j = 0; j < 12; ++j) {
            sc[j] = acc[j] + sb[6 + j];
            out1[base1 + 6 + j] = sc[j];
        }
        size_t base2 = (size_t)p * NA;
        #pragma unroll
        for (int a = 0; a < 6; ++a) {
            float d = sc[2 * a] - sc[2 * a + 1];
            out2[base2 + 3 + a] = 1.0f / (1.0f + __expf(d));
        }
    } else if (og == 2) {
        // loc 28..35 + scores 0..5
        float acc[14];
        rpn_accum<14>(xp, wbase, acc);
        size_t base0 = (size_t)p * NLOC + 28;
        #pragma unroll
        for (int j = 0; j < 8; ++j)
            out0[base0 + j] = acc[j] + lb[28 + j];
        float sc[6];
        size_t base1 = (size_t)p * NSC;
        #pragma unroll
        for (int j = 0; j < 6; ++j) {
            sc[j] = acc[8 + j] + sb[j];
            out1[base1 + j] = sc[j];
        }
        size_t base2 = (size_t)p * NA;
        #pragma unroll
        for (int a = 0; a < 3; ++a) {
            float d = sc[2 * a] - sc[2 * a + 1];
            out2[base2 + a] = 1.0f / (1.0f + __expf(d));
        }
    } else {
        // loc 14*og .. 14*og+13
        float acc[14];
        rpn_accum<14>(xp, wbase, acc);
        int ob = og * 14;
        size_t base0 = (size_t)p * NLOC + ob;
        #pragma unroll
        for (int j = 0; j < 14; ++j)
            out0[base0 + j] = acc[j] + lb[ob + j];
    }
}

extern "C" void kernel_launch(void* const* d_in, const int* in_sizes, int n_in,
                              void* d_out, int out_size, void* d_ws, size_t ws_size,
                              hipStream_t stream) {
    const float* x  = (const float*)d_in[0];
    const float* lw = (const float*)d_in[1];
    const float* lb = (const float*)d_in[2];
    const float* sw = (const float*)d_in[3];
    const float* sb = (const float*)d_in[4];

    float* out0 = (float*)d_out;                          // (16, 55296, 4)
    float* out1 = out0 + (size_t)NN * HW * NLOC;          // (16, 64, 96, 18)
    float* out2 = out1 + (size_t)NN * HW * NSC;           // (16, 55296)
    float* out3 = out2 + (size_t)NN * HW * NA;            // (55296, 4)

    float* wT3 = (float*)d_ws;   // 4*CC*16 floats = 128 KB

    int grid_t = (CC * 54 + 255) / 256;
    transpose_w_kernel<<<grid_t, 256, 0, stream>>>(lw, sw, wT3);

    int grid_a = (HW * NA + 255) / 256;
    anchors_kernel<<<grid_a, 256, 0, stream>>>(out3);

    int grid_m = NN * HW / 64;   // 1536 blocks * 4 waves
    rpn_main_kernel<<<grid_m, 256, 0, stream>>>(x, wT3, lb, sb, out0, out1, out2);
}